// Round 3
// baseline (612.467 us; speedup 1.0000x reference)
//
#include <hip/hip_runtime.h>
#include <stdint.h>

// ---------- types ----------
typedef unsigned short ushort_t;
typedef __bf16 bf16x8 __attribute__((ext_vector_type(8)));
typedef float f32x4 __attribute__((ext_vector_type(4)));
typedef float float4v __attribute__((ext_vector_type(4)));
typedef unsigned short ushort4v __attribute__((ext_vector_type(4)));

#define T_SEQ 2048
#define D_MODEL 2048
#define N_HEADS 16
#define HEAD_D 128
#define BATCH 2
#define M_ROWS (BATCH * T_SEQ)   // 4096

__device__ __forceinline__ ushort_t f2bf(float f) {
    unsigned u = __builtin_bit_cast(unsigned, f);
    u += 0x7fffu + ((u >> 16) & 1u);   // RNE
    return (ushort_t)(u >> 16);
}
__device__ __forceinline__ float bf2f(ushort_t h) {
    unsigned u = ((unsigned)h) << 16;
    return __builtin_bit_cast(float, u);
}

__device__ __forceinline__ void gload16(const ushort_t* g, ushort_t* l) {
    __builtin_amdgcn_global_load_lds(
        (const __attribute__((address_space(1))) void*)g,
        (__attribute__((address_space(3))) void*)l,
        16, 0, 0);
}

// ---------- cast x: f32 -> bf16 ----------
__global__ void cast_x_kernel(const float* __restrict__ x, ushort_t* __restrict__ xb, int n4) {
    int i = blockIdx.x * blockDim.x + threadIdx.x;
    if (i >= n4) return;
    float4v v = *(const float4v*)(x + (size_t)i * 4);
    ushort4v o;
    o[0] = f2bf(v[0]); o[1] = f2bf(v[1]); o[2] = f2bf(v[2]); o[3] = f2bf(v[3]);
    *(ushort4v*)(xb + (size_t)i * 4) = o;
}

// ---------- transpose + cast: W f32 [K][N] -> Wt bf16 [N][K] ----------
__global__ void tcast_kernel(const float* __restrict__ W, ushort_t* __restrict__ Wt, int K, int N) {
    __shared__ float tile[32][33];
    int n0 = blockIdx.x * 32, k0 = blockIdx.y * 32;
    int tx = threadIdx.x, ty = threadIdx.y;  // block (32,8)
#pragma unroll
    for (int i = 0; i < 4; ++i)
        tile[ty + i * 8][tx] = W[(size_t)(k0 + ty + i * 8) * N + n0 + tx];
    __syncthreads();
#pragma unroll
    for (int i = 0; i < 4; ++i)
        Wt[(size_t)(n0 + ty + i * 8) * K + k0 + tx] = f2bf(tile[tx][ty + i * 8]);
}

// ---------- GEMM: C[M,N] = A[M,K] (bf16 rm) x Bt[N,K] (bf16 rm, = B^T) ----------
template <int EPI>
__global__ __launch_bounds__(256) void gemm_bt(
    const ushort_t* __restrict__ A, const ushort_t* __restrict__ Bt,
    int M, int N, int K,
    ushort_t* __restrict__ o_q, ushort_t* __restrict__ o_k, ushort_t* __restrict__ o_vt,
    const float* __restrict__ b_gate, const ushort_t* __restrict__ atty,
    ushort_t* __restrict__ o_y, float* __restrict__ o_f32)
{
    __shared__ ushort_t As[128 * 64];
    __shared__ ushort_t Bs[128 * 64];
    const int tid = threadIdx.x;
    const int wid = tid >> 6, l = tid & 63;
    const int ln = l & 15, hi = l >> 4;
    const int wm = wid >> 1, wn = wid & 1;
    const int m0 = blockIdx.y * 128, n0 = blockIdx.x * 128;

    f32x4 acc[4][4];
#pragma unroll
    for (int m = 0; m < 4; ++m)
#pragma unroll
        for (int n = 0; n < 4; ++n) acc[m][n] = (f32x4){0.f, 0.f, 0.f, 0.f};

    const ushort_t* Ab = A + (size_t)(m0 + (tid >> 3)) * K + (tid & 7) * 8;
    const ushort_t* Bb = Bt + (size_t)(n0 + (tid >> 3)) * K + (tid & 7) * 8;
    ushort_t* As_w = As + wid * 512;
    ushort_t* Bs_w = Bs + wid * 512;

    for (int kt = 0; kt < K; kt += 64) {
        __syncthreads();
#pragma unroll
        for (int i = 0; i < 4; ++i) {
            gload16(Ab + (size_t)(i * 32) * K + kt, As_w + i * 2048);
            gload16(Bb + (size_t)(i * 32) * K + kt, Bs_w + i * 2048);
        }
        asm volatile("s_waitcnt vmcnt(0)" ::: "memory");
        __syncthreads();
#pragma unroll
        for (int kk = 0; kk < 2; ++kk) {
            bf16x8 af[4], bfg[4];
#pragma unroll
            for (int m = 0; m < 4; ++m)
                af[m] = *(const bf16x8*)(As + (wm * 64 + m * 16 + ln) * 64 + kk * 32 + hi * 8);
#pragma unroll
            for (int n = 0; n < 4; ++n)
                bfg[n] = *(const bf16x8*)(Bs + (wn * 64 + n * 16 + ln) * 64 + kk * 32 + hi * 8);
#pragma unroll
            for (int m = 0; m < 4; ++m)
#pragma unroll
                for (int n = 0; n < 4; ++n)
                    acc[m][n] = __builtin_amdgcn_mfma_f32_16x16x32_bf16(af[m], bfg[n], acc[m][n], 0, 0, 0);
        }
    }

    if (EPI == 0) {
        const int sec = n0 >> 11;
        const int h = (n0 & 2047) >> 7;
#pragma unroll
        for (int m = 0; m < 4; ++m)
#pragma unroll
            for (int n = 0; n < 4; ++n)
#pragma unroll
                for (int j = 0; j < 4; ++j) {
                    int grow = m0 + wm * 64 + m * 16 + hi * 4 + j;
                    int b = grow >> 11, t = grow & 2047;
                    int dd = wn * 64 + n * 16 + ln;
                    ushort_t val = f2bf(acc[m][n][j]);
                    size_t bh = (size_t)(b * N_HEADS + h);
                    if (sec == 0)      o_q[(bh * T_SEQ + t) * HEAD_D + dd] = val;
                    else if (sec == 1) o_k[(bh * T_SEQ + t) * HEAD_D + dd] = val;
                    else               o_vt[(bh * HEAD_D + dd) * T_SEQ + t] = val;
                }
    } else if (EPI == 1) {
#pragma unroll
        for (int m = 0; m < 4; ++m)
#pragma unroll
            for (int n = 0; n < 4; ++n)
#pragma unroll
                for (int j = 0; j < 4; ++j) {
                    int grow = m0 + wm * 64 + m * 16 + hi * 4 + j;
                    int gcol = n0 + wn * 64 + n * 16 + ln;
                    float g = acc[m][n][j] + b_gate[gcol];
                    g = 1.0f / (1.0f + __expf(-g));
                    size_t idx = (size_t)grow * D_MODEL + gcol;
                    o_y[idx] = f2bf(bf2f(atty[idx]) * g);
                }
    } else {
#pragma unroll
        for (int m = 0; m < 4; ++m)
#pragma unroll
            for (int n = 0; n < 4; ++n)
#pragma unroll
                for (int j = 0; j < 4; ++j) {
                    int grow = m0 + wm * 64 + m * 16 + hi * 4 + j;
                    int gcol = n0 + wn * 64 + n * 16 + ln;
                    o_f32[(size_t)grow * N + gcol] = acc[m][n][j];
                }
    }
}

// ---------- RMSNorm + RoPE, in place on q and k [B,H,T,128] ----------
__global__ __launch_bounds__(256) void rmsrope_kernel(ushort_t* __restrict__ qb, ushort_t* __restrict__ kb) {
    int wid = threadIdx.x >> 6, l = threadIdx.x & 63;
    int row = blockIdx.x * 4 + wid;          // (b*H + h)*T + t
    int t = row & (T_SEQ - 1);
    size_t base = (size_t)row * HEAD_D;

    float ang = (float)t * expf(-(float)l * 0.14391156f);
    float sv, cv;
    sincosf(ang, &sv, &cv);

    float a = bf2f(qb[base + l]), b = bf2f(qb[base + 64 + l]);
    float ss = a * a + b * b;
#pragma unroll
    for (int d = 1; d < 64; d <<= 1) ss += __shfl_xor(ss, d);
    float r = rsqrtf(ss * (1.0f / 128.0f) + 1e-6f);
    a *= r; b *= r;
    qb[base + l]      = f2bf(a * cv - b * sv);
    qb[base + 64 + l] = f2bf(a * sv + b * cv);

    a = bf2f(kb[base + l]); b = bf2f(kb[base + 64 + l]);
    ss = a * a + b * b;
#pragma unroll
    for (int d = 1; d < 64; d <<= 1) ss += __shfl_xor(ss, d);
    r = rsqrtf(ss * (1.0f / 128.0f) + 1e-6f);
    a *= r; b *= r;
    kb[base + l]      = f2bf(a * cv - b * sv);
    kb[base + 64 + l] = f2bf(a * sv + b * cv);
}

// ---------- causal flash attention v3 ----------
// 16-row q-tiles, 128 tiles x 32 bh = 4096 waves; grid (32,32) x 4 waves.
// Balanced: wave w of block bx owns tq {2bx, 127-2bx, 2bx+1, 126-2bx}[w]
// -> every block does exactly 33 kv-iterations.
// Fixed-max softmax: RMSNorm bounds |S*scale*log2e| <= 16.3, so exp2 without
// max subtraction is safe in f32/bf16 (softmax is shift-invariant; relative
// precision unchanged). No max reduce, no corr, no acc rescale.
// Row-sums kept as per-lane partials; single shfl reduce after the loop.
// Masking only on the diagonal tile (uniform branch).
__global__ __launch_bounds__(256) void flash_kernel(
    const ushort_t* __restrict__ qb, const ushort_t* __restrict__ kb,
    const ushort_t* __restrict__ vt, ushort_t* __restrict__ atty)
{
    const int bx = blockIdx.x, bh = blockIdx.y;
    const int wid = threadIdx.x >> 6, l = threadIdx.x & 63;
    const int ln = l & 15, hi = l >> 4;

    int tq;
    switch (wid) {
        case 0:  tq = 2 * bx;       break;
        case 1:  tq = 127 - 2 * bx; break;
        case 2:  tq = 2 * bx + 1;   break;
        default: tq = 126 - 2 * bx; break;
    }
    const int q0 = tq * 16;
    const int n_tiles = tq / 4 + 1;

    const ushort_t* Q  = qb + (size_t)bh * T_SEQ * HEAD_D;
    const ushort_t* Kp = kb + (size_t)bh * T_SEQ * HEAD_D;
    const ushort_t* Vp = vt + (size_t)bh * HEAD_D * T_SEQ;

    __shared__ ushort_t p_all[4][16][72];   // stride 144B = 9x16B: b128-aligned, conflict-light
    ushort_t (*p_lds)[72] = p_all[wid];

    bf16x8 qf[4];
#pragma unroll
    for (int kk = 0; kk < 4; ++kk)
        qf[kk] = *(const bf16x8*)(Q + (size_t)(q0 + ln) * HEAD_D + kk * 32 + hi * 8);

    f32x4 acc_o[8];
#pragma unroll
    for (int nd = 0; nd < 8; ++nd) acc_o[nd] = (f32x4){0.f, 0.f, 0.f, 0.f};
    float rl[4] = {0.f, 0.f, 0.f, 0.f};

    const float scale_log2 = 0.12752059520313818f;   // 1/sqrt(128) * log2(e)

    for (int it = 0; it < n_tiles; ++it) {
        const int kv0 = it * 64;
        const bool last_ = (it == n_tiles - 1);

        // ---- S = Q K^T ----
        f32x4 sa[4];
#pragma unroll
        for (int n = 0; n < 4; ++n) sa[n] = (f32x4){0.f, 0.f, 0.f, 0.f};
#pragma unroll
        for (int kk = 0; kk < 4; ++kk) {
            bf16x8 kf[4];
#pragma unroll
            for (int n = 0; n < 4; ++n)
                kf[n] = *(const bf16x8*)(Kp + (size_t)(kv0 + n * 16 + ln) * HEAD_D + kk * 32 + hi * 8);
#pragma unroll
            for (int n = 0; n < 4; ++n)
                sa[n] = __builtin_amdgcn_mfma_f32_16x16x32_bf16(qf[kk], kf[n], sa[n], 0, 0, 0);
        }

        // ---- hoist V (first kk2 half): latency hides under softmax ----
        bf16x8 vf0[8];
#pragma unroll
        for (int nd = 0; nd < 8; ++nd)
            vf0[nd] = *(const bf16x8*)(Vp + (size_t)(nd * 16 + ln) * T_SEQ + kv0 + hi * 8);

        // ---- fixed-max softmax: p = exp2(S*scale*log2e), per-lane partial sums ----
        if (last_) {
#pragma unroll
            for (int n = 0; n < 4; ++n)
#pragma unroll
                for (int j = 0; j < 4; ++j) {
                    int kv = kv0 + n * 16 + ln;
                    int qrow = q0 + hi * 4 + j;
                    float v = (kv <= qrow) ? sa[n][j] * scale_log2 : -1e30f;
                    float p = __builtin_amdgcn_exp2f(v);
                    rl[j] += p;
                    p_lds[hi * 4 + j][n * 16 + ln] = f2bf(p);
                }
        } else {
#pragma unroll
            for (int n = 0; n < 4; ++n)
#pragma unroll
                for (int j = 0; j < 4; ++j) {
                    float p = __builtin_amdgcn_exp2f(sa[n][j] * scale_log2);
                    rl[j] += p;
                    p_lds[hi * 4 + j][n * 16 + ln] = f2bf(p);
                }
        }

        asm volatile("s_waitcnt lgkmcnt(0)" ::: "memory");  // P writes visible (same wave)

        // ---- O += P V ----
        bf16x8 pA = *(const bf16x8*)(&p_lds[ln][hi * 8]);
#pragma unroll
        for (int nd = 0; nd < 8; ++nd)
            acc_o[nd] = __builtin_amdgcn_mfma_f32_16x16x32_bf16(pA, vf0[nd], acc_o[nd], 0, 0, 0);

        // second kv half: fully masked when last_ && tq%4 <= 1 -> skip
        if (!(last_ && (tq & 3) < 2)) {
            bf16x8 pB = *(const bf16x8*)(&p_lds[ln][32 + hi * 8]);
#pragma unroll
            for (int nd = 0; nd < 8; ++nd) {
                bf16x8 vf1 = *(const bf16x8*)(Vp + (size_t)(nd * 16 + ln) * T_SEQ + kv0 + 32 + hi * 8);
                acc_o[nd] = __builtin_amdgcn_mfma_f32_16x16x32_bf16(pB, vf1, acc_o[nd], 0, 0, 0);
            }
        }
    }

    // ---- row-sum reduce (once) ----
#pragma unroll
    for (int d = 1; d < 16; d <<= 1)
#pragma unroll
        for (int j = 0; j < 4; ++j)
            rl[j] += __shfl_xor(rl[j], d);

    // ---- epilogue ----
    const int b = bh >> 4, h = bh & 15;
#pragma unroll
    for (int j = 0; j < 4; ++j) {
        float inv = 1.0f / rl[j];
        int tr = q0 + hi * 4 + j;
#pragma unroll
        for (int nd = 0; nd < 8; ++nd)
            atty[((size_t)(b * T_SEQ + tr)) * D_MODEL + h * HEAD_D + nd * 16 + ln] =
                f2bf(acc_o[nd][j] * inv);
    }
}

// ---------- launch ----------
extern "C" void kernel_launch(void* const* d_in, const int* in_sizes, int n_in,
                              void* d_out, int out_size, void* d_ws, size_t ws_size,
                              hipStream_t stream) {
    const float* x      = (const float*)d_in[0];
    const float* W_qkv  = (const float*)d_in[1];
    const float* W_out  = (const float*)d_in[2];
    const float* W_gate = (const float*)d_in[3];
    const float* b_gate = (const float*)d_in[4];
    float* out = (float*)d_out;

    char* ws = (char*)d_ws;
    size_t off = 0;
    ushort_t* xb     = (ushort_t*)(ws + off); off += (size_t)M_ROWS * D_MODEL * 2;
    ushort_t* wqkvT  = (ushort_t*)(ws + off); off += (size_t)3 * D_MODEL * D_MODEL * 2;
    ushort_t* wgateT = (ushort_t*)(ws + off); off += (size_t)D_MODEL * D_MODEL * 2;
    ushort_t* woutT  = (ushort_t*)(ws + off); off += (size_t)D_MODEL * D_MODEL * 2;
    ushort_t* q_b    = (ushort_t*)(ws + off); off += (size_t)M_ROWS * D_MODEL * 2;
    ushort_t* k_b    = (ushort_t*)(ws + off); off += (size_t)M_ROWS * D_MODEL * 2;
    ushort_t* v_t    = (ushort_t*)(ws + off); off += (size_t)M_ROWS * D_MODEL * 2;
    ushort_t* atty   = (ushort_t*)(ws + off); off += (size_t)M_ROWS * D_MODEL * 2;
    ushort_t* y_b    = (ushort_t*)(ws + off); off += (size_t)M_ROWS * D_MODEL * 2;

    cast_x_kernel<<<8192, 256, 0, stream>>>(x, xb, (M_ROWS * D_MODEL) / 4);
    tcast_kernel<<<dim3(192, 64), dim3(32, 8), 0, stream>>>(W_qkv, wqkvT, D_MODEL, 3 * D_MODEL);
    tcast_kernel<<<dim3(64, 64), dim3(32, 8), 0, stream>>>(W_gate, wgateT, D_MODEL, D_MODEL);
    tcast_kernel<<<dim3(64, 64), dim3(32, 8), 0, stream>>>(W_out, woutT, D_MODEL, D_MODEL);
    gemm_bt<0><<<dim3(48, 32), 256, 0, stream>>>(xb, wqkvT, M_ROWS, 3 * D_MODEL, D_MODEL,
                                                 q_b, k_b, v_t, nullptr, nullptr, nullptr, nullptr);
    rmsrope_kernel<<<16384, 256, 0, stream>>>(q_b, k_b);
    flash_kernel<<<dim3(32, 32), 256, 0, stream>>>(q_b, k_b, v_t, atty);
    gemm_bt<1><<<dim3(16, 32), 256, 0, stream>>>(xb, wgateT, M_ROWS, D_MODEL, D_MODEL,
                                                 nullptr, nullptr, nullptr, b_gate, atty, y_b, nullptr);
    gemm_bt<2><<<dim3(16, 32), 256, 0, stream>>>(y_b, woutT, M_ROWS, D_MODEL, D_MODEL,
                                                 nullptr, nullptr, nullptr, nullptr, nullptr, nullptr, out);
}

// Round 6
// 389.046 us; speedup vs baseline: 1.5743x; 1.5743x over previous
//
#include <hip/hip_runtime.h>
#include <stdint.h>

// ---------- types ----------
typedef unsigned short ushort_t;
typedef __bf16 bf16x8 __attribute__((ext_vector_type(8)));
typedef float f32x4 __attribute__((ext_vector_type(4)));
typedef float float4v __attribute__((ext_vector_type(4)));
typedef unsigned short ushort4v __attribute__((ext_vector_type(4)));

#define T_SEQ 2048
#define D_MODEL 2048
#define N_HEADS 16
#define HEAD_D 128
#define BATCH 2
#define M_ROWS (BATCH * T_SEQ)   // 4096

__device__ __forceinline__ ushort_t f2bf(float f) {
    unsigned u = __builtin_bit_cast(unsigned, f);
    u += 0x7fffu + ((u >> 16) & 1u);   // RNE
    return (ushort_t)(u >> 16);
}
__device__ __forceinline__ float bf2f(ushort_t h) {
    unsigned u = ((unsigned)h) << 16;
    return __builtin_bit_cast(float, u);
}

__device__ __forceinline__ void gload16(const ushort_t* g, ushort_t* l) {
    __builtin_amdgcn_global_load_lds(
        (const __attribute__((address_space(1))) void*)g,
        (__attribute__((address_space(3))) void*)l,
        16, 0, 0);
}

#define SBAR0() __builtin_amdgcn_sched_barrier(0)

// ---------- cast x: f32 -> bf16 ----------
__global__ void cast_x_kernel(const float* __restrict__ x, ushort_t* __restrict__ xb, int n4) {
    int i = blockIdx.x * blockDim.x + threadIdx.x;
    if (i >= n4) return;
    float4v v = *(const float4v*)(x + (size_t)i * 4);
    ushort4v o;
    o[0] = f2bf(v[0]); o[1] = f2bf(v[1]); o[2] = f2bf(v[2]); o[3] = f2bf(v[3]);
    *(ushort4v*)(xb + (size_t)i * 4) = o;
}

// ---------- transpose + cast: W f32 [K][N] -> Wt bf16 [N][K] ----------
__global__ void tcast_kernel(const float* __restrict__ W, ushort_t* __restrict__ Wt, int K, int N) {
    __shared__ float tile[32][33];
    int n0 = blockIdx.x * 32, k0 = blockIdx.y * 32;
    int tx = threadIdx.x, ty = threadIdx.y;  // block (32,8)
#pragma unroll
    for (int i = 0; i < 4; ++i)
        tile[ty + i * 8][tx] = W[(size_t)(k0 + ty + i * 8) * N + n0 + tx];
    __syncthreads();
#pragma unroll
    for (int i = 0; i < 4; ++i)
        Wt[(size_t)(n0 + ty + i * 8) * K + k0 + tx] = f2bf(tile[tx][ty + i * 8]);
}

// ---------- GEMM: C[M,N] = A[M,K] (bf16 rm) x Bt[N,K] (bf16 rm, = B^T) ----------
template <int EPI>
__global__ __launch_bounds__(256) void gemm_bt(
    const ushort_t* __restrict__ A, const ushort_t* __restrict__ Bt,
    int M, int N, int K,
    ushort_t* __restrict__ o_q, ushort_t* __restrict__ o_k, ushort_t* __restrict__ o_vt,
    const float* __restrict__ b_gate, const ushort_t* __restrict__ atty,
    ushort_t* __restrict__ o_y, float* __restrict__ o_f32)
{
    __shared__ ushort_t As[128 * 64];
    __shared__ ushort_t Bs[128 * 64];
    const int tid = threadIdx.x;
    const int wid = tid >> 6, l = tid & 63;
    const int ln = l & 15, hi = l >> 4;
    const int wm = wid >> 1, wn = wid & 1;
    const int m0 = blockIdx.y * 128, n0 = blockIdx.x * 128;

    f32x4 acc[4][4];
#pragma unroll
    for (int m = 0; m < 4; ++m)
#pragma unroll
        for (int n = 0; n < 4; ++n) acc[m][n] = (f32x4){0.f, 0.f, 0.f, 0.f};

    const ushort_t* Ab = A + (size_t)(m0 + (tid >> 3)) * K + (tid & 7) * 8;
    const ushort_t* Bb = Bt + (size_t)(n0 + (tid >> 3)) * K + (tid & 7) * 8;
    ushort_t* As_w = As + wid * 512;
    ushort_t* Bs_w = Bs + wid * 512;

    for (int kt = 0; kt < K; kt += 64) {
        __syncthreads();
#pragma unroll
        for (int i = 0; i < 4; ++i) {
            gload16(Ab + (size_t)(i * 32) * K + kt, As_w + i * 2048);
            gload16(Bb + (size_t)(i * 32) * K + kt, Bs_w + i * 2048);
        }
        asm volatile("s_waitcnt vmcnt(0)" ::: "memory");
        __syncthreads();
#pragma unroll
        for (int kk = 0; kk < 2; ++kk) {
            bf16x8 af[4], bfg[4];
#pragma unroll
            for (int m = 0; m < 4; ++m)
                af[m] = *(const bf16x8*)(As + (wm * 64 + m * 16 + ln) * 64 + kk * 32 + hi * 8);
#pragma unroll
            for (int n = 0; n < 4; ++n)
                bfg[n] = *(const bf16x8*)(Bs + (wn * 64 + n * 16 + ln) * 64 + kk * 32 + hi * 8);
#pragma unroll
            for (int m = 0; m < 4; ++m)
#pragma unroll
                for (int n = 0; n < 4; ++n)
                    acc[m][n] = __builtin_amdgcn_mfma_f32_16x16x32_bf16(af[m], bfg[n], acc[m][n], 0, 0, 0);
        }
    }

    if (EPI == 0) {
        const int sec = n0 >> 11;
        const int h = (n0 & 2047) >> 7;
#pragma unroll
        for (int m = 0; m < 4; ++m)
#pragma unroll
            for (int n = 0; n < 4; ++n)
#pragma unroll
                for (int j = 0; j < 4; ++j) {
                    int grow = m0 + wm * 64 + m * 16 + hi * 4 + j;
                    int b = grow >> 11, t = grow & 2047;
                    int dd = wn * 64 + n * 16 + ln;
                    ushort_t val = f2bf(acc[m][n][j]);
                    size_t bh = (size_t)(b * N_HEADS + h);
                    if (sec == 0)      o_q[(bh * T_SEQ + t) * HEAD_D + dd] = val;
                    else if (sec == 1) o_k[(bh * T_SEQ + t) * HEAD_D + dd] = val;
                    else               o_vt[(bh * HEAD_D + dd) * T_SEQ + t] = val;
                }
    } else if (EPI == 1) {
#pragma unroll
        for (int m = 0; m < 4; ++m)
#pragma unroll
            for (int n = 0; n < 4; ++n)
#pragma unroll
                for (int j = 0; j < 4; ++j) {
                    int grow = m0 + wm * 64 + m * 16 + hi * 4 + j;
                    int gcol = n0 + wn * 64 + n * 16 + ln;
                    float g = acc[m][n][j] + b_gate[gcol];
                    g = 1.0f / (1.0f + __expf(-g));
                    size_t idx = (size_t)grow * D_MODEL + gcol;
                    o_y[idx] = f2bf(bf2f(atty[idx]) * g);
                }
    } else {
#pragma unroll
        for (int m = 0; m < 4; ++m)
#pragma unroll
            for (int n = 0; n < 4; ++n)
#pragma unroll
                for (int j = 0; j < 4; ++j) {
                    int grow = m0 + wm * 64 + m * 16 + hi * 4 + j;
                    int gcol = n0 + wn * 64 + n * 16 + ln;
                    o_f32[(size_t)grow * N + gcol] = acc[m][n][j];
                }
    }
}

// ---------- RMSNorm + RoPE, in place on q and k [B,H,T,128] ----------
__global__ __launch_bounds__(256) void rmsrope_kernel(ushort_t* __restrict__ qb, ushort_t* __restrict__ kb) {
    int wid = threadIdx.x >> 6, l = threadIdx.x & 63;
    int row = blockIdx.x * 4 + wid;          // (b*H + h)*T + t
    int t = row & (T_SEQ - 1);
    size_t base = (size_t)row * HEAD_D;

    float ang = (float)t * expf(-(float)l * 0.14391156f);
    float sv, cv;
    sincosf(ang, &sv, &cv);

    float a = bf2f(qb[base + l]), b = bf2f(qb[base + 64 + l]);
    float ss = a * a + b * b;
#pragma unroll
    for (int d = 1; d < 64; d <<= 1) ss += __shfl_xor(ss, d);
    float r = rsqrtf(ss * (1.0f / 128.0f) + 1e-6f);
    a *= r; b *= r;
    qb[base + l]      = f2bf(a * cv - b * sv);
    qb[base + 64 + l] = f2bf(a * sv + b * cv);

    a = bf2f(kb[base + l]); b = bf2f(kb[base + 64 + l]);
    ss = a * a + b * b;
#pragma unroll
    for (int d = 1; d < 64; d <<= 1) ss += __shfl_xor(ss, d);
    r = rsqrtf(ss * (1.0f / 128.0f) + 1e-6f);
    a *= r; b *= r;
    kb[base + l]      = f2bf(a * cv - b * sv);
    kb[base + 64 + l] = f2bf(a * sv + b * cv);
}

// ---------- causal flash attention v6 ----------
// = v5 with the mask-gate fix: a tile is `partial` iff kv0+63 > q0w (smallest
// q-row of the WAVE), not q0w+31. v5's `+31` let waves 1 and 3 skip masking
// on their diagonal tile -> deterministic corruption (absmax 0.30 in R4/R5).
__global__ __launch_bounds__(256) void flash_kernel(
    const ushort_t* __restrict__ qb, const ushort_t* __restrict__ kb,
    const ushort_t* __restrict__ vt, ushort_t* __restrict__ atty)
{
    const int bh = blockIdx.x, bxp = blockIdx.y;
    const int tid = threadIdx.x;
    const int wid = tid >> 6, l = tid & 63;
    const int ln = l & 15, hi = l >> 4;
    const int lnx = (ln & 7) << 4;            // read-side swizzle (row&7 == ln&7)

    const ushort_t* Q  = qb + (size_t)bh * T_SEQ * HEAD_D;
    const ushort_t* Kp = kb + (size_t)bh * T_SEQ * HEAD_D;
    const ushort_t* Vp = vt + (size_t)bh * HEAD_D * T_SEQ;

    __shared__ ushort_t Ks[4][64 * 128];      // 64 KB
    __shared__ ushort_t Vs[4][128 * 64];      // 64 KB
    __shared__ ushort_t p_all[4][32][72];     // 18 KB
    ushort_t (*p_lds)[72] = p_all[wid];

    const float scale_log2 = 0.12752059520313818f;   // 1/sqrt(128) * log2(e)
    const int bb = bh >> 4, h = bh & 15;

    // per-thread staging geometry (involution: LDS[x] = G[x ^ sw(x)])
    int s_off[4], s_ksrc[4], s_vrow[4], s_vcol[4];
#pragma unroll
    for (int i = 0; i < 4; ++i) {
        int off = (i * 256 + tid) * 16;                    // byte offset in 16 KB tile
        s_off[i] = (i * 4 + wid) * 512;                    // LDS dst (elems), wave-uniform
        int krow = off >> 8;
        s_ksrc[i] = off ^ ((krow & 7) << 4);               // K src byte (256 B rows)
        int vrow = off >> 7;
        s_vrow[i] = vrow;
        s_vcol[i] = ((off & 127) ^ ((vrow & 7) << 4)) >> 1; // V src col elems (128 B rows)
    }

#define STAGE(kvbase, Kd, Vd)                                                            \
    {                                                                                    \
        _Pragma("unroll")                                                                \
        for (int i_ = 0; i_ < 4; ++i_) {                                                 \
            gload16((const ushort_t*)((const char*)(Kp + (size_t)(kvbase) * HEAD_D) +    \
                                      s_ksrc[i_]), (Kd) + s_off[i_]);                    \
            gload16(Vp + (size_t)s_vrow[i_] * T_SEQ + (kvbase) + s_vcol[i_],             \
                    (Vd) + s_off[i_]);                                                   \
        }                                                                                \
    }

    for (int pass = 0; pass < 2; ++pass) {
        const int qt = pass ? (15 - bxp) : bxp;
        const int q0w = qt * 128 + wid * 32;
        const int nt = 2 * qt + 2;               // >= 2 always

        bf16x8 qf[2][4];
#pragma unroll
        for (int m = 0; m < 2; ++m)
#pragma unroll
            for (int kk = 0; kk < 4; ++kk)
                qf[m][kk] = *(const bf16x8*)(Q + (size_t)(q0w + m * 16 + ln) * HEAD_D + kk * 32 + hi * 8);

        f32x4 acc_o[2][8];
#pragma unroll
        for (int m = 0; m < 2; ++m)
#pragma unroll
            for (int nd = 0; nd < 8; ++nd) acc_o[m][nd] = (f32x4){0.f, 0.f, 0.f, 0.f};
        float rl[2][4];
#pragma unroll
        for (int m = 0; m < 2; ++m)
#pragma unroll
            for (int j = 0; j < 4; ++j) rl[m][j] = 0.f;

        ushort_t *Ka = Ks[0], *Kb = Ks[1], *Kc = Ks[2], *Kd4 = Ks[3];
        ushort_t *Va = Vs[0], *Vb = Vs[1], *Vc = Vs[2], *Vd4 = Vs[3];

        // prologue: tiles 0 and 1 (nt >= 2)
        STAGE(0, Ka, Va);
        STAGE(64, Kb, Vb);

        for (int t = 0; t < nt; ++t) {
            const int kv0 = t * 64;
            if (t + 2 < nt) {
                STAGE(kv0 + 128, Kc, Vc);
                asm volatile("s_waitcnt vmcnt(16)" ::: "memory");   // tile t landed; t+1,t+2 in flight
            } else if (t + 1 < nt) {
                asm volatile("s_waitcnt vmcnt(8)" ::: "memory");    // tile t landed; t+1 in flight
            } else {
                asm volatile("s_waitcnt vmcnt(0)" ::: "memory");
            }
            SBAR0();
            __builtin_amdgcn_s_barrier();
            SBAR0();

            if (kv0 <= q0w + 31) {
                const ushort_t* Ksc = Ka;
                const ushort_t* Vsc = Va;

                // ---- S = Q K^T ----
                f32x4 sa[2][4];
#pragma unroll
                for (int m = 0; m < 2; ++m)
#pragma unroll
                    for (int n = 0; n < 4; ++n) sa[m][n] = (f32x4){0.f, 0.f, 0.f, 0.f};
#pragma unroll
                for (int kk = 0; kk < 4; ++kk) {
                    bf16x8 kf[4];
#pragma unroll
                    for (int n = 0; n < 4; ++n)
                        kf[n] = *(const bf16x8*)((const char*)Ksc +
                                 ((((n * 16 + ln) << 8) + (kk << 6) + (hi << 4)) ^ lnx));
#pragma unroll
                    for (int m = 0; m < 2; ++m)
#pragma unroll
                        for (int n = 0; n < 4; ++n)
                            sa[m][n] = __builtin_amdgcn_mfma_f32_16x16x32_bf16(qf[m][kk], kf[n], sa[m][n], 0, 0, 0);
                }

                // ---- fixed-max softmax ----
                // FIX: tile needs masking iff it contains kv > q0w (smallest q-row
                // of this wave). v5's `q0w + 31` skipped the diagonal tile for
                // waves with q0w % 64 == 32 (waves 1,3).
                const bool partial = (kv0 + 63 > q0w);
                if (partial) {
#pragma unroll
                    for (int m = 0; m < 2; ++m)
#pragma unroll
                        for (int n = 0; n < 4; ++n)
#pragma unroll
                            for (int j = 0; j < 4; ++j) {
                                int kv = kv0 + n * 16 + ln;
                                int qrow = q0w + m * 16 + hi * 4 + j;
                                float v = (kv <= qrow) ? sa[m][n][j] * scale_log2 : -1e30f;
                                float p = __builtin_amdgcn_exp2f(v);
                                rl[m][j] += p;
                                p_lds[m * 16 + hi * 4 + j][n * 16 + ln] = f2bf(p);
                            }
                } else {
#pragma unroll
                    for (int m = 0; m < 2; ++m)
#pragma unroll
                        for (int n = 0; n < 4; ++n)
#pragma unroll
                            for (int j = 0; j < 4; ++j) {
                                float p = __builtin_amdgcn_exp2f(sa[m][n][j] * scale_log2);
                                rl[m][j] += p;
                                p_lds[m * 16 + hi * 4 + j][n * 16 + ln] = f2bf(p);
                            }
                }
                asm volatile("s_waitcnt lgkmcnt(0)" ::: "memory");  // wave's P writes done
                SBAR0();

                // ---- O += P V ----
                const bool skipB = (kv0 + 32 > q0w + 31);
                bf16x8 pf[2][2];
#pragma unroll
                for (int m = 0; m < 2; ++m)
#pragma unroll
                    for (int kk2 = 0; kk2 < 2; ++kk2)
                        pf[m][kk2] = *(const bf16x8*)(&p_lds[m * 16 + ln][kk2 * 32 + hi * 8]);
#pragma unroll
                for (int nd = 0; nd < 8; ++nd) {
                    bf16x8 vf = *(const bf16x8*)((const char*)Vsc +
                                 ((((nd * 16 + ln) << 7) + (hi << 4)) ^ lnx));
                    acc_o[0][nd] = __builtin_amdgcn_mfma_f32_16x16x32_bf16(pf[0][0], vf, acc_o[0][nd], 0, 0, 0);
                    acc_o[1][nd] = __builtin_amdgcn_mfma_f32_16x16x32_bf16(pf[1][0], vf, acc_o[1][nd], 0, 0, 0);
                }
                if (!skipB) {
#pragma unroll
                    for (int nd = 0; nd < 8; ++nd) {
                        bf16x8 vf = *(const bf16x8*)((const char*)Vsc +
                                     ((((nd * 16 + ln) << 7) + 64 + (hi << 4)) ^ lnx));
                        acc_o[0][nd] = __builtin_amdgcn_mfma_f32_16x16x32_bf16(pf[0][1], vf, acc_o[0][nd], 0, 0, 0);
                        acc_o[1][nd] = __builtin_amdgcn_mfma_f32_16x16x32_bf16(pf[1][1], vf, acc_o[1][nd], 0, 0, 0);
                    }
                }
            }
            asm volatile("s_waitcnt lgkmcnt(0)" ::: "memory");  // all LDS reads retired
            SBAR0();
            __builtin_amdgcn_s_barrier();
            SBAR0();
            // rotate 4-buffer ring
            ushort_t* tK = Ka; Ka = Kb; Kb = Kc; Kc = Kd4; Kd4 = tK;
            ushort_t* tV = Va; Va = Vb; Vb = Vc; Vc = Vd4; Vd4 = tV;
        }

        // ---- row-sum reduce + store ----
#pragma unroll
        for (int d = 1; d < 16; d <<= 1)
#pragma unroll
            for (int m = 0; m < 2; ++m)
#pragma unroll
                for (int j = 0; j < 4; ++j)
                    rl[m][j] += __shfl_xor(rl[m][j], d);

#pragma unroll
        for (int m = 0; m < 2; ++m)
#pragma unroll
            for (int j = 0; j < 4; ++j) {
                float inv = 1.0f / rl[m][j];
                int tr = q0w + m * 16 + hi * 4 + j;
#pragma unroll
                for (int nd = 0; nd < 8; ++nd)
                    atty[((size_t)(bb * T_SEQ + tr)) * D_MODEL + h * HEAD_D + nd * 16 + ln] =
                        f2bf(acc_o[m][nd][j] * inv);
            }
    }
#undef STAGE
}

// ---------- launch ----------
extern "C" void kernel_launch(void* const* d_in, const int* in_sizes, int n_in,
                              void* d_out, int out_size, void* d_ws, size_t ws_size,
                              hipStream_t stream) {
    const float* x      = (const float*)d_in[0];
    const float* W_qkv  = (const float*)d_in[1];
    const float* W_out  = (const float*)d_in[2];
    const float* W_gate = (const float*)d_in[3];
    const float* b_gate = (const float*)d_in[4];
    float* out = (float*)d_out;

    char* ws = (char*)d_ws;
    size_t off = 0;
    ushort_t* xb     = (ushort_t*)(ws + off); off += (size_t)M_ROWS * D_MODEL * 2;
    ushort_t* wqkvT  = (ushort_t*)(ws + off); off += (size_t)3 * D_MODEL * D_MODEL * 2;
    ushort_t* wgateT = (ushort_t*)(ws + off); off += (size_t)D_MODEL * D_MODEL * 2;
    ushort_t* woutT  = (ushort_t*)(ws + off); off += (size_t)D_MODEL * D_MODEL * 2;
    ushort_t* q_b    = (ushort_t*)(ws + off); off += (size_t)M_ROWS * D_MODEL * 2;
    ushort_t* k_b    = (ushort_t*)(ws + off); off += (size_t)M_ROWS * D_MODEL * 2;
    ushort_t* v_t    = (ushort_t*)(ws + off); off += (size_t)M_ROWS * D_MODEL * 2;
    ushort_t* atty   = (ushort_t*)(ws + off); off += (size_t)M_ROWS * D_MODEL * 2;
    ushort_t* y_b    = (ushort_t*)(ws + off); off += (size_t)M_ROWS * D_MODEL * 2;

    cast_x_kernel<<<8192, 256, 0, stream>>>(x, xb, (M_ROWS * D_MODEL) / 4);
    tcast_kernel<<<dim3(192, 64), dim3(32, 8), 0, stream>>>(W_qkv, wqkvT, D_MODEL, 3 * D_MODEL);
    tcast_kernel<<<dim3(64, 64), dim3(32, 8), 0, stream>>>(W_gate, wgateT, D_MODEL, D_MODEL);
    tcast_kernel<<<dim3(64, 64), dim3(32, 8), 0, stream>>>(W_out, woutT, D_MODEL, D_MODEL);
    gemm_bt<0><<<dim3(48, 32), 256, 0, stream>>>(xb, wqkvT, M_ROWS, 3 * D_MODEL, D_MODEL,
                                                 q_b, k_b, v_t, nullptr, nullptr, nullptr, nullptr);
    rmsrope_kernel<<<16384, 256, 0, stream>>>(q_b, k_b);
    flash_kernel<<<dim3(32, 8), 256, 0, stream>>>(q_b, k_b, v_t, atty);
    gemm_bt<1><<<dim3(16, 32), 256, 0, stream>>>(xb, wgateT, M_ROWS, D_MODEL, D_MODEL,
                                                 nullptr, nullptr, nullptr, b_gate, atty, y_b, nullptr);
    gemm_bt<2><<<dim3(16, 32), 256, 0, stream>>>(y_b, woutT, M_ROWS, D_MODEL, D_MODEL,
                                                 nullptr, nullptr, nullptr, nullptr, nullptr, nullptr, out);
}

// Round 7
// 344.891 us; speedup vs baseline: 1.7758x; 1.1280x over previous
//
#include <hip/hip_runtime.h>
#include <stdint.h>

// ---------- types ----------
typedef unsigned short ushort_t;
typedef __bf16 bf16x8 __attribute__((ext_vector_type(8)));
typedef float f32x4 __attribute__((ext_vector_type(4)));
typedef float float4v __attribute__((ext_vector_type(4)));
typedef unsigned short ushort4v __attribute__((ext_vector_type(4)));

#define T_SEQ 2048
#define D_MODEL 2048
#define N_HEADS 16
#define HEAD_D 128
#define BATCH 2
#define M_ROWS (BATCH * T_SEQ)   // 4096

__device__ __forceinline__ ushort_t f2bf(float f) {
    unsigned u = __builtin_bit_cast(unsigned, f);
    u += 0x7fffu + ((u >> 16) & 1u);   // RNE
    return (ushort_t)(u >> 16);
}
__device__ __forceinline__ float bf2f(ushort_t h) {
    unsigned u = ((unsigned)h) << 16;
    return __builtin_bit_cast(float, u);
}

__device__ __forceinline__ void gload16(const ushort_t* g, ushort_t* l) {
    __builtin_amdgcn_global_load_lds(
        (const __attribute__((address_space(1))) void*)g,
        (__attribute__((address_space(3))) void*)l,
        16, 0, 0);
}

#define SBAR0() __builtin_amdgcn_sched_barrier(0)

// ---------- cast x: f32 -> bf16 ----------
__global__ void cast_x_kernel(const float* __restrict__ x, ushort_t* __restrict__ xb, int n4) {
    int i = blockIdx.x * blockDim.x + threadIdx.x;
    if (i >= n4) return;
    float4v v = *(const float4v*)(x + (size_t)i * 4);
    ushort4v o;
    o[0] = f2bf(v[0]); o[1] = f2bf(v[1]); o[2] = f2bf(v[2]); o[3] = f2bf(v[3]);
    *(ushort4v*)(xb + (size_t)i * 4) = o;
}

// ---------- transpose + cast: W f32 [K][N] -> Wt bf16 [N][K] ----------
__global__ void tcast_kernel(const float* __restrict__ W, ushort_t* __restrict__ Wt, int K, int N) {
    __shared__ float tile[32][33];
    int n0 = blockIdx.x * 32, k0 = blockIdx.y * 32;
    int tx = threadIdx.x, ty = threadIdx.y;  // block (32,8)
#pragma unroll
    for (int i = 0; i < 4; ++i)
        tile[ty + i * 8][tx] = W[(size_t)(k0 + ty + i * 8) * N + n0 + tx];
    __syncthreads();
#pragma unroll
    for (int i = 0; i < 4; ++i)
        Wt[(size_t)(n0 + ty + i * 8) * K + k0 + tx] = f2bf(tile[tx][ty + i * 8]);
}

// ---------- GEMM v2: C[M,N] = A[M,K] (bf16 rm) x Bt[N,K] (bf16 rm, = B^T) ----------
// 128x128 tile, BK=64, 4 waves (2x2 of 64x64). Changes vs v1:
//  - T2 both-sides XOR swizzle (byte ^= (row&7)<<4): pre-swizzled global src
//    col + same XOR on ds_read (involution). Kills the 16-way 128B-stride
//    conflict (37.7M/dispatch in R6).
//  - stage-early + counted vmcnt(8) + LDS double buffer (no drain in loop);
//    WAR separation = lgkmcnt(0) + s_barrier, SBAR0-pinned.
//  - setprio(1) around MFMA cluster; bijective XCD block swizzle (nwg%8==0).
template <int EPI>
__global__ __launch_bounds__(256) void gemm_bt(
    const ushort_t* __restrict__ A, const ushort_t* __restrict__ Bt,
    int M, int N, int K,
    ushort_t* __restrict__ o_q, ushort_t* __restrict__ o_k, ushort_t* __restrict__ o_vt,
    const float* __restrict__ b_gate, const ushort_t* __restrict__ atty,
    ushort_t* __restrict__ o_y, float* __restrict__ o_f32)
{
    __shared__ ushort_t As[2][128 * 64];
    __shared__ ushort_t Bs[2][128 * 64];
    const int tid = threadIdx.x;
    const int wid = tid >> 6, l = tid & 63;
    const int ln = l & 15, hi = l >> 4;
    const int lnx = (ln & 7) << 4;            // read-side swizzle term
    const int wm = wid >> 1, wn = wid & 1;

    // XCD-aware bijective block swizzle (all our grids: nwg % 8 == 0)
    const int gx = gridDim.x;
    const int nwg = gx * gridDim.y;
    int lin = blockIdx.y * gx + blockIdx.x;
    lin = (lin & 7) * (nwg >> 3) + (lin >> 3);
    const int m0 = (lin / gx) * 128, n0 = (lin % gx) * 128;

    f32x4 acc[4][4];
#pragma unroll
    for (int m = 0; m < 4; ++m)
#pragma unroll
        for (int n = 0; n < 4; ++n) acc[m][n] = (f32x4){0.f, 0.f, 0.f, 0.f};

    // staging geometry: thread covers rows srow + i*32, pre-swizzled col
    const int srow = tid >> 3;                       // 0..31
    const int scol = ((tid & 7) ^ (srow & 7)) << 3;  // elems (srow&7 invariant under +32)
    const ushort_t* Ag = A + (size_t)(m0 + srow) * K + scol;
    const ushort_t* Bg = Bt + (size_t)(n0 + srow) * K + scol;

#define GSTAGE(ktb, Ad, Bd)                                                   \
    {                                                                         \
        _Pragma("unroll")                                                     \
        for (int i_ = 0; i_ < 4; ++i_) {                                      \
            gload16(Ag + (size_t)(i_ * 32) * K + (ktb), (Ad) + i_ * 2048);    \
            gload16(Bg + (size_t)(i_ * 32) * K + (ktb), (Bd) + i_ * 2048);    \
        }                                                                     \
    }

    const int nkt = K >> 6;
    int cur = 0;
    GSTAGE(0, As[0] + wid * 512, Bs[0] + wid * 512);

    for (int t = 0; t < nkt; ++t) {
        if (t + 1 < nkt) {
            GSTAGE((t + 1) << 6, As[cur ^ 1] + wid * 512, Bs[cur ^ 1] + wid * 512);
            asm volatile("s_waitcnt vmcnt(8)" ::: "memory");   // tile t landed; t+1 in flight
        } else {
            asm volatile("s_waitcnt vmcnt(0)" ::: "memory");
        }
        SBAR0();
        __builtin_amdgcn_s_barrier();
        SBAR0();

        const char* Ab_ = (const char*)As[cur];
        const char* Bb_ = (const char*)Bs[cur];
        __builtin_amdgcn_s_setprio(1);
#pragma unroll
        for (int kk = 0; kk < 2; ++kk) {
            bf16x8 af[4], bfg[4];
#pragma unroll
            for (int m = 0; m < 4; ++m)
                af[m] = *(const bf16x8*)(Ab_ + (((wm * 64 + m * 16 + ln) << 7) +
                                                (((kk << 6) + (hi << 4)) ^ lnx)));
#pragma unroll
            for (int n = 0; n < 4; ++n)
                bfg[n] = *(const bf16x8*)(Bb_ + (((wn * 64 + n * 16 + ln) << 7) +
                                                 (((kk << 6) + (hi << 4)) ^ lnx)));
#pragma unroll
            for (int m = 0; m < 4; ++m)
#pragma unroll
                for (int n = 0; n < 4; ++n)
                    acc[m][n] = __builtin_amdgcn_mfma_f32_16x16x32_bf16(af[m], bfg[n], acc[m][n], 0, 0, 0);
        }
        __builtin_amdgcn_s_setprio(0);
        asm volatile("s_waitcnt lgkmcnt(0)" ::: "memory");  // all LDS reads retired
        SBAR0();
        __builtin_amdgcn_s_barrier();
        SBAR0();
        cur ^= 1;
    }
#undef GSTAGE

    if (EPI == 0) {
        const int sec = n0 >> 11;
        const int h = (n0 & 2047) >> 7;
#pragma unroll
        for (int m = 0; m < 4; ++m)
#pragma unroll
            for (int n = 0; n < 4; ++n)
#pragma unroll
                for (int j = 0; j < 4; ++j) {
                    int grow = m0 + wm * 64 + m * 16 + hi * 4 + j;
                    int b = grow >> 11, t = grow & 2047;
                    int dd = wn * 64 + n * 16 + ln;
                    ushort_t val = f2bf(acc[m][n][j]);
                    size_t bh = (size_t)(b * N_HEADS + h);
                    if (sec == 0)      o_q[(bh * T_SEQ + t) * HEAD_D + dd] = val;
                    else if (sec == 1) o_k[(bh * T_SEQ + t) * HEAD_D + dd] = val;
                    else               o_vt[(bh * HEAD_D + dd) * T_SEQ + t] = val;
                }
    } else if (EPI == 1) {
#pragma unroll
        for (int m = 0; m < 4; ++m)
#pragma unroll
            for (int n = 0; n < 4; ++n)
#pragma unroll
                for (int j = 0; j < 4; ++j) {
                    int grow = m0 + wm * 64 + m * 16 + hi * 4 + j;
                    int gcol = n0 + wn * 64 + n * 16 + ln;
                    float g = acc[m][n][j] + b_gate[gcol];
                    g = 1.0f / (1.0f + __expf(-g));
                    size_t idx = (size_t)grow * D_MODEL + gcol;
                    o_y[idx] = f2bf(bf2f(atty[idx]) * g);
                }
    } else {
#pragma unroll
        for (int m = 0; m < 4; ++m)
#pragma unroll
            for (int n = 0; n < 4; ++n)
#pragma unroll
                for (int j = 0; j < 4; ++j) {
                    int grow = m0 + wm * 64 + m * 16 + hi * 4 + j;
                    int gcol = n0 + wn * 64 + n * 16 + ln;
                    o_f32[(size_t)grow * N + gcol] = acc[m][n][j];
                }
    }
}

// ---------- RMSNorm + RoPE, in place on q and k [B,H,T,128] ----------
__global__ __launch_bounds__(256) void rmsrope_kernel(ushort_t* __restrict__ qb, ushort_t* __restrict__ kb) {
    int wid = threadIdx.x >> 6, l = threadIdx.x & 63;
    int row = blockIdx.x * 4 + wid;          // (b*H + h)*T + t
    int t = row & (T_SEQ - 1);
    size_t base = (size_t)row * HEAD_D;

    float ang = (float)t * expf(-(float)l * 0.14391156f);
    float sv, cv;
    sincosf(ang, &sv, &cv);

    float a = bf2f(qb[base + l]), b = bf2f(qb[base + 64 + l]);
    float ss = a * a + b * b;
#pragma unroll
    for (int d = 1; d < 64; d <<= 1) ss += __shfl_xor(ss, d);
    float r = rsqrtf(ss * (1.0f / 128.0f) + 1e-6f);
    a *= r; b *= r;
    qb[base + l]      = f2bf(a * cv - b * sv);
    qb[base + 64 + l] = f2bf(a * sv + b * cv);

    a = bf2f(kb[base + l]); b = bf2f(kb[base + 64 + l]);
    ss = a * a + b * b;
#pragma unroll
    for (int d = 1; d < 64; d <<= 1) ss += __shfl_xor(ss, d);
    r = rsqrtf(ss * (1.0f / 128.0f) + 1e-6f);
    a *= r; b *= r;
    kb[base + l]      = f2bf(a * cv - b * sv);
    kb[base + 64 + l] = f2bf(a * sv + b * cv);
}

// ---------- causal flash attention v6 (unchanged from R6 passing version) ----------
__global__ __launch_bounds__(256) void flash_kernel(
    const ushort_t* __restrict__ qb, const ushort_t* __restrict__ kb,
    const ushort_t* __restrict__ vt, ushort_t* __restrict__ atty)
{
    const int bh = blockIdx.x, bxp = blockIdx.y;
    const int tid = threadIdx.x;
    const int wid = tid >> 6, l = tid & 63;
    const int ln = l & 15, hi = l >> 4;
    const int lnx = (ln & 7) << 4;            // read-side swizzle (row&7 == ln&7)

    const ushort_t* Q  = qb + (size_t)bh * T_SEQ * HEAD_D;
    const ushort_t* Kp = kb + (size_t)bh * T_SEQ * HEAD_D;
    const ushort_t* Vp = vt + (size_t)bh * HEAD_D * T_SEQ;

    __shared__ ushort_t Ks[4][64 * 128];      // 64 KB
    __shared__ ushort_t Vs[4][128 * 64];      // 64 KB
    __shared__ ushort_t p_all[4][32][72];     // 18 KB
    ushort_t (*p_lds)[72] = p_all[wid];

    const float scale_log2 = 0.12752059520313818f;   // 1/sqrt(128) * log2(e)
    const int bb = bh >> 4, h = bh & 15;

    // per-thread staging geometry (involution: LDS[x] = G[x ^ sw(x)])
    int s_off[4], s_ksrc[4], s_vrow[4], s_vcol[4];
#pragma unroll
    for (int i = 0; i < 4; ++i) {
        int off = (i * 256 + tid) * 16;                    // byte offset in 16 KB tile
        s_off[i] = (i * 4 + wid) * 512;                    // LDS dst (elems), wave-uniform
        int krow = off >> 8;
        s_ksrc[i] = off ^ ((krow & 7) << 4);               // K src byte (256 B rows)
        int vrow = off >> 7;
        s_vrow[i] = vrow;
        s_vcol[i] = ((off & 127) ^ ((vrow & 7) << 4)) >> 1; // V src col elems (128 B rows)
    }

#define STAGE(kvbase, Kd, Vd)                                                            \
    {                                                                                    \
        _Pragma("unroll")                                                                \
        for (int i_ = 0; i_ < 4; ++i_) {                                                 \
            gload16((const ushort_t*)((const char*)(Kp + (size_t)(kvbase) * HEAD_D) +    \
                                      s_ksrc[i_]), (Kd) + s_off[i_]);                    \
            gload16(Vp + (size_t)s_vrow[i_] * T_SEQ + (kvbase) + s_vcol[i_],             \
                    (Vd) + s_off[i_]);                                                   \
        }                                                                                \
    }

    for (int pass = 0; pass < 2; ++pass) {
        const int qt = pass ? (15 - bxp) : bxp;
        const int q0w = qt * 128 + wid * 32;
        const int nt = 2 * qt + 2;               // >= 2 always

        bf16x8 qf[2][4];
#pragma unroll
        for (int m = 0; m < 2; ++m)
#pragma unroll
            for (int kk = 0; kk < 4; ++kk)
                qf[m][kk] = *(const bf16x8*)(Q + (size_t)(q0w + m * 16 + ln) * HEAD_D + kk * 32 + hi * 8);

        f32x4 acc_o[2][8];
#pragma unroll
        for (int m = 0; m < 2; ++m)
#pragma unroll
            for (int nd = 0; nd < 8; ++nd) acc_o[m][nd] = (f32x4){0.f, 0.f, 0.f, 0.f};
        float rl[2][4];
#pragma unroll
        for (int m = 0; m < 2; ++m)
#pragma unroll
            for (int j = 0; j < 4; ++j) rl[m][j] = 0.f;

        ushort_t *Ka = Ks[0], *Kb = Ks[1], *Kc = Ks[2], *Kd4 = Ks[3];
        ushort_t *Va = Vs[0], *Vb = Vs[1], *Vc = Vs[2], *Vd4 = Vs[3];

        // prologue: tiles 0 and 1 (nt >= 2)
        STAGE(0, Ka, Va);
        STAGE(64, Kb, Vb);

        for (int t = 0; t < nt; ++t) {
            const int kv0 = t * 64;
            if (t + 2 < nt) {
                STAGE(kv0 + 128, Kc, Vc);
                asm volatile("s_waitcnt vmcnt(16)" ::: "memory");   // tile t landed; t+1,t+2 in flight
            } else if (t + 1 < nt) {
                asm volatile("s_waitcnt vmcnt(8)" ::: "memory");    // tile t landed; t+1 in flight
            } else {
                asm volatile("s_waitcnt vmcnt(0)" ::: "memory");
            }
            SBAR0();
            __builtin_amdgcn_s_barrier();
            SBAR0();

            if (kv0 <= q0w + 31) {
                const ushort_t* Ksc = Ka;
                const ushort_t* Vsc = Va;

                // ---- S = Q K^T ----
                f32x4 sa[2][4];
#pragma unroll
                for (int m = 0; m < 2; ++m)
#pragma unroll
                    for (int n = 0; n < 4; ++n) sa[m][n] = (f32x4){0.f, 0.f, 0.f, 0.f};
#pragma unroll
                for (int kk = 0; kk < 4; ++kk) {
                    bf16x8 kf[4];
#pragma unroll
                    for (int n = 0; n < 4; ++n)
                        kf[n] = *(const bf16x8*)((const char*)Ksc +
                                 ((((n * 16 + ln) << 8) + (kk << 6) + (hi << 4)) ^ lnx));
#pragma unroll
                    for (int m = 0; m < 2; ++m)
#pragma unroll
                        for (int n = 0; n < 4; ++n)
                            sa[m][n] = __builtin_amdgcn_mfma_f32_16x16x32_bf16(qf[m][kk], kf[n], sa[m][n], 0, 0, 0);
                }

                // ---- fixed-max softmax (tile is partial iff it contains kv > q0w) ----
                const bool partial = (kv0 + 63 > q0w);
                if (partial) {
#pragma unroll
                    for (int m = 0; m < 2; ++m)
#pragma unroll
                        for (int n = 0; n < 4; ++n)
#pragma unroll
                            for (int j = 0; j < 4; ++j) {
                                int kv = kv0 + n * 16 + ln;
                                int qrow = q0w + m * 16 + hi * 4 + j;
                                float v = (kv <= qrow) ? sa[m][n][j] * scale_log2 : -1e30f;
                                float p = __builtin_amdgcn_exp2f(v);
                                rl[m][j] += p;
                                p_lds[m * 16 + hi * 4 + j][n * 16 + ln] = f2bf(p);
                            }
                } else {
#pragma unroll
                    for (int m = 0; m < 2; ++m)
#pragma unroll
                        for (int n = 0; n < 4; ++n)
#pragma unroll
                            for (int j = 0; j < 4; ++j) {
                                float p = __builtin_amdgcn_exp2f(sa[m][n][j] * scale_log2);
                                rl[m][j] += p;
                                p_lds[m * 16 + hi * 4 + j][n * 16 + ln] = f2bf(p);
                            }
                }
                asm volatile("s_waitcnt lgkmcnt(0)" ::: "memory");  // wave's P writes done
                SBAR0();

                // ---- O += P V ----
                const bool skipB = (kv0 + 32 > q0w + 31);
                bf16x8 pf[2][2];
#pragma unroll
                for (int m = 0; m < 2; ++m)
#pragma unroll
                    for (int kk2 = 0; kk2 < 2; ++kk2)
                        pf[m][kk2] = *(const bf16x8*)(&p_lds[m * 16 + ln][kk2 * 32 + hi * 8]);
#pragma unroll
                for (int nd = 0; nd < 8; ++nd) {
                    bf16x8 vf = *(const bf16x8*)((const char*)Vsc +
                                 ((((nd * 16 + ln) << 7) + (hi << 4)) ^ lnx));
                    acc_o[0][nd] = __builtin_amdgcn_mfma_f32_16x16x32_bf16(pf[0][0], vf, acc_o[0][nd], 0, 0, 0);
                    acc_o[1][nd] = __builtin_amdgcn_mfma_f32_16x16x32_bf16(pf[1][0], vf, acc_o[1][nd], 0, 0, 0);
                }
                if (!skipB) {
#pragma unroll
                    for (int nd = 0; nd < 8; ++nd) {
                        bf16x8 vf = *(const bf16x8*)((const char*)Vsc +
                                     ((((nd * 16 + ln) << 7) + 64 + (hi << 4)) ^ lnx));
                        acc_o[0][nd] = __builtin_amdgcn_mfma_f32_16x16x32_bf16(pf[0][1], vf, acc_o[0][nd], 0, 0, 0);
                        acc_o[1][nd] = __builtin_amdgcn_mfma_f32_16x16x32_bf16(pf[1][1], vf, acc_o[1][nd], 0, 0, 0);
                    }
                }
            }
            asm volatile("s_waitcnt lgkmcnt(0)" ::: "memory");  // all LDS reads retired
            SBAR0();
            __builtin_amdgcn_s_barrier();
            SBAR0();
            // rotate 4-buffer ring
            ushort_t* tK = Ka; Ka = Kb; Kb = Kc; Kc = Kd4; Kd4 = tK;
            ushort_t* tV = Va; Va = Vb; Vb = Vc; Vc = Vd4; Vd4 = tV;
        }

        // ---- row-sum reduce + store ----
#pragma unroll
        for (int d = 1; d < 16; d <<= 1)
#pragma unroll
            for (int m = 0; m < 2; ++m)
#pragma unroll
                for (int j = 0; j < 4; ++j)
                    rl[m][j] += __shfl_xor(rl[m][j], d);

#pragma unroll
        for (int m = 0; m < 2; ++m)
#pragma unroll
            for (int j = 0; j < 4; ++j) {
                float inv = 1.0f / rl[m][j];
                int tr = q0w + m * 16 + hi * 4 + j;
#pragma unroll
                for (int nd = 0; nd < 8; ++nd)
                    atty[((size_t)(bb * T_SEQ + tr)) * D_MODEL + h * HEAD_D + nd * 16 + ln] =
                        f2bf(acc_o[m][nd][j] * inv);
            }
    }
#undef STAGE
}

// ---------- launch ----------
extern "C" void kernel_launch(void* const* d_in, const int* in_sizes, int n_in,
                              void* d_out, int out_size, void* d_ws, size_t ws_size,
                              hipStream_t stream) {
    const float* x      = (const float*)d_in[0];
    const float* W_qkv  = (const float*)d_in[1];
    const float* W_out  = (const float*)d_in[2];
    const float* W_gate = (const float*)d_in[3];
    const float* b_gate = (const float*)d_in[4];
    float* out = (float*)d_out;

    char* ws = (char*)d_ws;
    size_t off = 0;
    ushort_t* xb     = (ushort_t*)(ws + off); off += (size_t)M_ROWS * D_MODEL * 2;
    ushort_t* wqkvT  = (ushort_t*)(ws + off); off += (size_t)3 * D_MODEL * D_MODEL * 2;
    ushort_t* wgateT = (ushort_t*)(ws + off); off += (size_t)D_MODEL * D_MODEL * 2;
    ushort_t* woutT  = (ushort_t*)(ws + off); off += (size_t)D_MODEL * D_MODEL * 2;
    ushort_t* q_b    = (ushort_t*)(ws + off); off += (size_t)M_ROWS * D_MODEL * 2;
    ushort_t* k_b    = (ushort_t*)(ws + off); off += (size_t)M_ROWS * D_MODEL * 2;
    ushort_t* v_t    = (ushort_t*)(ws + off); off += (size_t)M_ROWS * D_MODEL * 2;
    ushort_t* atty   = (ushort_t*)(ws + off); off += (size_t)M_ROWS * D_MODEL * 2;
    ushort_t* y_b    = (ushort_t*)(ws + off); off += (size_t)M_ROWS * D_MODEL * 2;

    cast_x_kernel<<<8192, 256, 0, stream>>>(x, xb, (M_ROWS * D_MODEL) / 4);
    tcast_kernel<<<dim3(192, 64), dim3(32, 8), 0, stream>>>(W_qkv, wqkvT, D_MODEL, 3 * D_MODEL);
    tcast_kernel<<<dim3(64, 64), dim3(32, 8), 0, stream>>>(W_gate, wgateT, D_MODEL, D_MODEL);
    tcast_kernel<<<dim3(64, 64), dim3(32, 8), 0, stream>>>(W_out, woutT, D_MODEL, D_MODEL);
    gemm_bt<0><<<dim3(48, 32), 256, 0, stream>>>(xb, wqkvT, M_ROWS, 3 * D_MODEL, D_MODEL,
                                                 q_b, k_b, v_t, nullptr, nullptr, nullptr, nullptr);
    rmsrope_kernel<<<16384, 256, 0, stream>>>(q_b, k_b);
    flash_kernel<<<dim3(32, 8), 256, 0, stream>>>(q_b, k_b, v_t, atty);
    gemm_bt<1><<<dim3(16, 32), 256, 0, stream>>>(xb, wgateT, M_ROWS, D_MODEL, D_MODEL,
                                                 nullptr, nullptr, nullptr, b_gate, atty, y_b, nullptr);
    gemm_bt<2><<<dim3(16, 32), 256, 0, stream>>>(y_b, woutT, M_ROWS, D_MODEL, D_MODEL,
                                                 nullptr, nullptr, nullptr, nullptr, nullptr, nullptr, out);
}